// Round 7
// baseline (570.677 us; speedup 1.0000x reference)
//
#include <hip/hip_runtime.h>
#include <hip/hip_bf16.h>
#include <math.h>

#define NH   32
#define NKV  8
#define HDIM 128
#define BATCH 2
#define SEQ  1024
#define KSUB 256
#define DSUB 16
#define PQM  8

typedef __attribute__((ext_vector_type(8))) _Float16 f16x8;
typedef __attribute__((ext_vector_type(8))) short bf16x8;
typedef __attribute__((ext_vector_type(4))) short bf16x4;
typedef __attribute__((ext_vector_type(4))) float f32x4;
typedef __attribute__((address_space(3))) short lds_short;

__device__ inline short f2bf(float x) {
    unsigned u = __builtin_bit_cast(unsigned, x);
    unsigned r = (u + 0x7fff + ((u >> 16) & 1)) >> 16;
    return (short)r;
}

__device__ inline void gload_lds16(const void* g, void* l) {
    __builtin_amdgcn_global_load_lds(
        (const __attribute__((address_space(1))) unsigned*)g,
        (__attribute__((address_space(3))) unsigned*)l, 16, 0, 0);
}

__device__ inline bf16x4 tr16(unsigned byte_addr) {
    bf16x4 r;
    asm volatile("ds_read_b64_tr_b16 %0, %1" : "=v"(r) : "v"(byte_addr));
    return r;
}

// ---------------------------------------------------------------------------
// fp32 -> fp16 2-term split, 8 elems/thread: x = hi + mid * 2^-12.
// ---------------------------------------------------------------------------
__global__ void split_f16(const float* __restrict__ x,
                          _Float16* __restrict__ hi, _Float16* __restrict__ mid,
                          int n8)
{
    int i = blockIdx.x * 256 + threadIdx.x;
    if (i < n8) {
        float4 v0 = ((const float4*)x)[2*i];
        float4 v1 = ((const float4*)x)[2*i + 1];
        float v[8] = {v0.x, v0.y, v0.z, v0.w, v1.x, v1.y, v1.z, v1.w};
        f16x8 h, m;
        #pragma unroll
        for (int j = 0; j < 8; j++) {
            _Float16 hh = (_Float16)v[j];
            h[j] = hh;
            m[j] = (_Float16)((v[j] - (float)hh) * 4096.f);
        }
        ((f16x8*)hi)[i]  = h;
        ((f16x8*)mid)[i] = m;
    }
}

__global__ void cast_f16(const float* __restrict__ x, _Float16* __restrict__ y, int n8)
{
    int i = blockIdx.x * 256 + threadIdx.x;
    if (i < n8) {
        float4 v0 = ((const float4*)x)[2*i];
        float4 v1 = ((const float4*)x)[2*i + 1];
        float v[8] = {v0.x, v0.y, v0.z, v0.w, v1.x, v1.y, v1.z, v1.w};
        f16x8 h;
        #pragma unroll
        for (int j = 0; j < 8; j++) h[j] = (_Float16)v[j];
        ((f16x8*)y)[i] = h;
    }
}

// ---------------------------------------------------------------------------
// KV projection, 3-pass precision-split, split-K=2, double-buffered LDS with
// STAGE-ahead + granule-XOR swizzle (linear gload_lds dest, inverse-swizzled
// global source k-chunk; read granule = l4 ^ ((l15>>1)&3)).
// ---------------------------------------------------------------------------
__global__ __launch_bounds__(256, 2) void gemm_kv_3p(
    const _Float16* __restrict__ Ahi, const _Float16* __restrict__ Ami,
    const _Float16* __restrict__ Whi, const _Float16* __restrict__ Wmi,
    float* __restrict__ Cp)
{
    __shared__ _Float16 sAh[2][128 * 32];
    __shared__ _Float16 sAm[2][128 * 32];
    __shared__ _Float16 sWh[2][128 * 32];
    __shared__ _Float16 sWm[2][128 * 32];

    const int tid = threadIdx.x;
    const int wid = tid >> 6, lane = tid & 63;
    const int l15 = lane & 15, l4 = lane >> 4;
    const int col0 = blockIdx.x * 128, row0 = blockIdx.y * 128;
    const int kz = blockIdx.z;
    const int wr = (wid >> 1) * 64, wc = (wid & 1) * 64;
    const int cx8 = (l4 ^ ((l15 >> 1) & 3)) * 8;   // swizzled read granule

    f32x4 am[4][4], ax[4][4];
    #pragma unroll
    for (int m = 0; m < 4; m++)
        #pragma unroll
        for (int n = 0; n < 4; n++) { am[m][n] = (f32x4)0.f; ax[m][n] = (f32x4)0.f; }

    const int ci0 = tid, ci1 = tid + 256;
    const int r0 = ci0 >> 2, c0 = ((ci0 & 3) ^ ((ci0 >> 3) & 3)) * 8;
    const int r1 = ci1 >> 2, c1 = ((ci1 & 3) ^ ((ci1 >> 3) & 3)) * 8;
    const size_t kb = (size_t)kz * 2048;
    const _Float16* pAh0 = Ahi + (size_t)(row0 + r0) * 4096 + kb + c0;
    const _Float16* pAh1 = Ahi + (size_t)(row0 + r1) * 4096 + kb + c1;
    const _Float16* pAm0 = Ami + (size_t)(row0 + r0) * 4096 + kb + c0;
    const _Float16* pAm1 = Ami + (size_t)(row0 + r1) * 4096 + kb + c1;
    const _Float16* pWh0 = Whi + (size_t)(col0 + r0) * 4096 + kb + c0;
    const _Float16* pWh1 = Whi + (size_t)(col0 + r1) * 4096 + kb + c1;
    const _Float16* pWm0 = Wmi + (size_t)(col0 + r0) * 4096 + kb + c0;
    const _Float16* pWm1 = Wmi + (size_t)(col0 + r1) * 4096 + kb + c1;

    auto STAGE = [&](int bs, int k0) {
        gload_lds16(pAh0 + k0, &sAh[bs][0] + ci0 * 8);
        gload_lds16(pAh1 + k0, &sAh[bs][0] + ci1 * 8);
        gload_lds16(pAm0 + k0, &sAm[bs][0] + ci0 * 8);
        gload_lds16(pAm1 + k0, &sAm[bs][0] + ci1 * 8);
        gload_lds16(pWh0 + k0, &sWh[bs][0] + ci0 * 8);
        gload_lds16(pWh1 + k0, &sWh[bs][0] + ci1 * 8);
        gload_lds16(pWm0 + k0, &sWm[bs][0] + ci0 * 8);
        gload_lds16(pWm1 + k0, &sWm[bs][0] + ci1 * 8);
    };

    STAGE(0, 0);
    __syncthreads();
    int cur = 0;

    for (int k0 = 0; k0 < 2048; k0 += 32) {
        if (k0 + 32 < 2048) STAGE(cur ^ 1, k0 + 32);

        f16x8 ah[4], amv[4], bh[4], bm[4];
        #pragma unroll
        for (int m = 0; m < 4; m++) {
            ah[m]  = *(const f16x8*)(&sAh[cur][0] + (wr + m*16 + l15) * 32 + cx8);
            amv[m] = *(const f16x8*)(&sAm[cur][0] + (wr + m*16 + l15) * 32 + cx8);
        }
        #pragma unroll
        for (int n = 0; n < 4; n++) {
            bh[n] = *(const f16x8*)(&sWh[cur][0] + (wc + n*16 + l15) * 32 + cx8);
            bm[n] = *(const f16x8*)(&sWm[cur][0] + (wc + n*16 + l15) * 32 + cx8);
        }
        #pragma unroll
        for (int m = 0; m < 4; m++)
            #pragma unroll
            for (int n = 0; n < 4; n++) {
                am[m][n] = __builtin_amdgcn_mfma_f32_16x16x32_f16(ah[m],  bh[n], am[m][n], 0, 0, 0);
                ax[m][n] = __builtin_amdgcn_mfma_f32_16x16x32_f16(ah[m],  bm[n], ax[m][n], 0, 0, 0);
                ax[m][n] = __builtin_amdgcn_mfma_f32_16x16x32_f16(amv[m], bh[n], ax[m][n], 0, 0, 0);
            }
        __syncthreads();
        cur ^= 1;
    }

    float* base = Cp + (size_t)kz * 2048 * 2048;
    const float s = 1.f / 4096.f;
    #pragma unroll
    for (int m = 0; m < 4; m++) {
        #pragma unroll
        for (int r = 0; r < 4; r++) {
            float* p = base + (size_t)(row0 + wr + m*16 + l4*4 + r) * 2048 + col0 + wc + l15;
            #pragma unroll
            for (int n = 0; n < 4; n++)
                p[n * 16] = am[m][n][r] + ax[m][n][r] * s;
        }
    }
}

// ---------------------------------------------------------------------------
// Split-K reduce + bias, fused K-RoPE. (unchanged)
// ---------------------------------------------------------------------------
__global__ void kv_reduce(float* __restrict__ KVp,
                          const float* __restrict__ bK, const float* __restrict__ bV,
                          const float* __restrict__ cosT, const float* __restrict__ sinT)
{
    int t = blockIdx.x * 256 + threadIdx.x;
    float* P0 = KVp;
    const float* P1 = KVp + (size_t)2048 * 2048;
    if (blockIdx.y == 0) {
        int i  = t & 63;
        int h  = (t >> 6) & 7;
        int rr = t >> 9;
        int s  = rr & (SEQ - 1);
        size_t o = (size_t)rr * 2048 + h * 128 + i;
        float x1 = P0[o]      + P1[o]      + bK[h*128 + i];
        float x2 = P0[o + 64] + P1[o + 64] + bK[h*128 + i + 64];
        float c  = cosT[s*64 + i];
        float sv = sinT[s*64 + i];
        P0[o]      = x1 * c - x2 * sv;
        P0[o + 64] = x2 * c + x1 * sv;
    } else {
        int j  = t & 511;
        int rr = t >> 9;
        size_t o = (size_t)rr * 2048 + 1024 + j;
        P0[o]       = P0[o]       + P1[o]       + bV[j];
        P0[o + 512] = P0[o + 512] + P1[o + 512] + bV[j + 512];
    }
}

// ---------------------------------------------------------------------------
// Q projection with fused RoPE + scale + bf16 output; dbuf + swizzle.
// ---------------------------------------------------------------------------
__global__ __launch_bounds__(256) void gemm_q_rope(
    const _Float16* __restrict__ A, const _Float16* __restrict__ W,
    const float* __restrict__ bias, __hip_bfloat16* __restrict__ Qbf,
    const float* __restrict__ cosT, const float* __restrict__ sinT)
{
    __shared__ _Float16 Al[2][128 * 32];
    __shared__ _Float16 Bl[2][128 * 32];

    const int tid = threadIdx.x;
    const int wid = tid >> 6, lane = tid & 63;
    const int l15 = lane & 15, l4 = lane >> 4;
    const int row0 = blockIdx.y * 128, col0 = blockIdx.x * 128;
    const int wr = (wid >> 1) * 64, wc = (wid & 1) * 32;
    const int K = 4096;
    const int cx8 = (l4 ^ ((l15 >> 1) & 3)) * 8;

    f32x4 acc[4][4];
    #pragma unroll
    for (int m = 0; m < 4; m++)
        #pragma unroll
        for (int n = 0; n < 4; n++) acc[m][n] = (f32x4)0.f;

    const int ci0 = tid, ci1 = tid + 256;
    const int r0 = ci0 >> 2, c0 = ((ci0 & 3) ^ ((ci0 >> 3) & 3)) * 8;
    const int r1 = ci1 >> 2, c1 = ((ci1 & 3) ^ ((ci1 >> 3) & 3)) * 8;
    const _Float16* Ag0 = A + (size_t)(row0 + r0) * K + c0;
    const _Float16* Ag1 = A + (size_t)(row0 + r1) * K + c1;
    const _Float16* Wg0 = W + (size_t)(col0 + r0) * K + c0;
    const _Float16* Wg1 = W + (size_t)(col0 + r1) * K + c1;

    auto STAGE = [&](int bs, int k0) {
        gload_lds16(Ag0 + k0, &Al[bs][0] + ci0 * 8);
        gload_lds16(Ag1 + k0, &Al[bs][0] + ci1 * 8);
        gload_lds16(Wg0 + k0, &Bl[bs][0] + ci0 * 8);
        gload_lds16(Wg1 + k0, &Bl[bs][0] + ci1 * 8);
    };

    STAGE(0, 0);
    __syncthreads();
    int cur = 0;

    for (int k0 = 0; k0 < K; k0 += 32) {
        if (k0 + 32 < K) STAGE(cur ^ 1, k0 + 32);

        f16x8 af[4], bfr[4];
        #pragma unroll
        for (int m = 0; m < 4; m++)
            af[m] = *(const f16x8*)(&Al[cur][0] + (wr + m*16 + l15) * 32 + cx8);
        #pragma unroll
        for (int n = 0; n < 4; n++) {
            int fc = wc + (n & 1) * 16 + (n >> 1) * 64;
            bfr[n] = *(const f16x8*)(&Bl[cur][0] + (fc + l15) * 32 + cx8);
        }
        #pragma unroll
        for (int m = 0; m < 4; m++)
            #pragma unroll
            for (int n = 0; n < 4; n++)
                acc[m][n] = __builtin_amdgcn_mfma_f32_16x16x32_f16(af[m], bfr[n], acc[m][n], 0, 0, 0);
        __syncthreads();
        cur ^= 1;
    }

    const float scale = 0.08838834764831845f;
    #pragma unroll
    for (int m = 0; m < 4; m++) {
        #pragma unroll
        for (int r = 0; r < 4; r++) {
            int rr = row0 + wr + m*16 + l4*4 + r;
            int s  = rr & (SEQ - 1);
            #pragma unroll
            for (int n = 0; n < 2; n++) {
                int i = wc + n*16 + l15;
                float x1 = acc[m][n][r]     + bias[col0 + i];
                float x2 = acc[m][n + 2][r] + bias[col0 + i + 64];
                float c  = cosT[s*64 + i];
                float sv = sinT[s*64 + i];
                Qbf[(size_t)rr * 4096 + col0 + i]      = __float2bfloat16((x1*c - x2*sv) * scale);
                Qbf[(size_t)rr * 4096 + col0 + i + 64] = __float2bfloat16((x2*c + x1*sv) * scale);
            }
        }
    }
}

// ---------------------------------------------------------------------------
// 1-pass fp16 MFMA GEMM (O projection); dbuf + swizzle.
// ---------------------------------------------------------------------------
__global__ __launch_bounds__(256) void gemm_f16_1p(
    const _Float16* __restrict__ A, const _Float16* __restrict__ W,
    float* __restrict__ C, int N, int K)
{
    __shared__ _Float16 Al[2][128 * 32];
    __shared__ _Float16 Bl[2][128 * 32];

    const int tid = threadIdx.x;
    const int wid = tid >> 6, lane = tid & 63;
    const int l15 = lane & 15, l4 = lane >> 4;
    const int row0 = blockIdx.y * 128, col0 = blockIdx.x * 128;
    const int wr = (wid >> 1) * 64, wc = (wid & 1) * 64;
    const int cx8 = (l4 ^ ((l15 >> 1) & 3)) * 8;

    f32x4 acc[4][4];
    #pragma unroll
    for (int m = 0; m < 4; m++)
        #pragma unroll
        for (int n = 0; n < 4; n++) acc[m][n] = (f32x4)0.f;

    const int ci0 = tid, ci1 = tid + 256;
    const int r0 = ci0 >> 2, c0 = ((ci0 & 3) ^ ((ci0 >> 3) & 3)) * 8;
    const int r1 = ci1 >> 2, c1 = ((ci1 & 3) ^ ((ci1 >> 3) & 3)) * 8;
    const _Float16* Ag0 = A + (size_t)(row0 + r0) * K + c0;
    const _Float16* Ag1 = A + (size_t)(row0 + r1) * K + c1;
    const _Float16* Wg0 = W + (size_t)(col0 + r0) * K + c0;
    const _Float16* Wg1 = W + (size_t)(col0 + r1) * K + c1;

    auto STAGE = [&](int bs, int k0) {
        gload_lds16(Ag0 + k0, &Al[bs][0] + ci0 * 8);
        gload_lds16(Ag1 + k0, &Al[bs][0] + ci1 * 8);
        gload_lds16(Wg0 + k0, &Bl[bs][0] + ci0 * 8);
        gload_lds16(Wg1 + k0, &Bl[bs][0] + ci1 * 8);
    };

    STAGE(0, 0);
    __syncthreads();
    int cur = 0;

    for (int k0 = 0; k0 < K; k0 += 32) {
        if (k0 + 32 < K) STAGE(cur ^ 1, k0 + 32);

        f16x8 af[4], bfr[4];
        #pragma unroll
        for (int m = 0; m < 4; m++)
            af[m] = *(const f16x8*)(&Al[cur][0] + (wr + m*16 + l15) * 32 + cx8);
        #pragma unroll
        for (int n = 0; n < 4; n++)
            bfr[n] = *(const f16x8*)(&Bl[cur][0] + (wc + n*16 + l15) * 32 + cx8);
        #pragma unroll
        for (int m = 0; m < 4; m++)
            #pragma unroll
            for (int n = 0; n < 4; n++)
                acc[m][n] = __builtin_amdgcn_mfma_f32_16x16x32_f16(af[m], bfr[n], acc[m][n], 0, 0, 0);
        __syncthreads();
        cur ^= 1;
    }

    #pragma unroll
    for (int m = 0; m < 4; m++) {
        #pragma unroll
        for (int r = 0; r < 4; r++) {
            float* Cp = C + (size_t)(row0 + wr + m*16 + l4*4 + r) * N + col0 + wc + l15;
            #pragma unroll
            for (int n = 0; n < 4; n++)
                Cp[n * 16] = acc[m][n][r];
        }
    }
}

// ---------------------------------------------------------------------------
__global__ void rope_table(float* __restrict__ cosT, float* __restrict__ sinT)
{
    int idx = blockIdx.x * 256 + threadIdx.x;
    int s = idx >> 6, i = idx & 63;
    float inv_f = (float)pow(1.0e6, -(double)i / 64.0);
    float freq  = (float)s * inv_f;
    cosT[idx] = (float)cos((double)freq);
    sinT[idx] = (float)sin((double)freq);
}

// ---------------------------------------------------------------------------
// PQ round-trip, 4 lanes per item, interleaved centroid partition k=i*4+j.
// Cross-lane merge: strictly smaller d2 wins, ties -> smaller k (= jnp.argmin
// first-min semantics). grid (256, PQM), 64 items/block.
// ---------------------------------------------------------------------------
__global__ __launch_bounds__(256) void pq_kernel(
    const float* __restrict__ X, const float* __restrict__ cent,
    __hip_bfloat16* __restrict__ rec, int ldx)
{
    __shared__ float Cs[KSUB * DSUB];
    __shared__ float CC[KSUB];
    const int m = blockIdx.y;
    const float* cm = cent + (size_t)m * KSUB * DSUB;
    for (int t = threadIdx.x; t < KSUB * DSUB; t += 256) Cs[t] = cm[t];
    __syncthreads();
    {
        int k = threadIdx.x;
        float s = 0.f;
        #pragma unroll
        for (int d = 0; d < DSUB; d++) s += Cs[k*DSUB + d] * Cs[k*DSUB + d];
        CC[k] = s;
    }
    __syncthreads();

    const int tid = threadIdx.x;
    const int j   = tid & 3;
    const int p   = blockIdx.x * 64 + (tid >> 2);
    const int s_  = p & (SEQ - 1);
    const int bh  = p >> 10;
    const int b   = bh >> 3, h = bh & 7;
    const float* x = X + (size_t)(b*SEQ + s_) * ldx + h*HDIM + m*DSUB;

    float xv[DSUB], xx = 0.f;
    #pragma unroll
    for (int d = 0; d < DSUB; d++) { xv[d] = x[d]; xx += xv[d]*xv[d]; }

    float best = INFINITY; int bk = 0;
    #pragma unroll 4
    for (int i = 0; i < 64; i++) {
        int k = i*4 + j;
        float dot = 0.f;
        #pragma unroll
        for (int d = 0; d < DSUB; d++) dot += xv[d] * Cs[k*DSUB + d];
        float d2 = xx + CC[k] - 2.f * dot;
        if (d2 < best) { best = d2; bk = k; }
    }

    #pragma unroll
    for (int off = 1; off < 4; off <<= 1) {
        float ob = __shfl_xor(best, off, 64);
        int   ok = __shfl_xor(bk,   off, 64);
        if (ob < best || (ob == best && ok < bk)) { best = ob; bk = ok; }
    }

    __hip_bfloat16* r = rec + (size_t)(b*SEQ + s_) * (NKV*HDIM) + h*HDIM + m*DSUB;
    #pragma unroll
    for (int d = 0; d < 4; d++)
        r[j*4 + d] = __float2bfloat16(Cs[bk*DSUB + j*4 + d]);
}

// ---------------------------------------------------------------------------
// MFMA flash attention (unchanged from round 6).
// ---------------------------------------------------------------------------
__global__ __launch_bounds__(256) void attn_mfma(
    const short* __restrict__ K, const short* __restrict__ V,
    const short* __restrict__ Qbf, _Float16* __restrict__ O)
{
    __shared__ short Ks[2][64 * 128];
    __shared__ short Vs[2][64 * 128];
    __shared__ short Ps[4][16 * 72];

    const int tid = threadIdx.x;
    const int wid = tid >> 6, lane = tid & 63;
    const int l15 = lane & 15, l4 = lane >> 4;
    const int qt  = gridDim.x - 1 - blockIdx.x;
    const int qb  = qt * 64;
    const int h   = blockIdx.y & 31, b = blockIdx.y >> 5;
    const int kvh = h >> 2;
    const int qw  = qb + wid * 16;

    bf16x8 qf[4];
    {
        const short* qp = Qbf + (size_t)(b*SEQ + qw + l15) * 4096 + h*HDIM + l4*8;
        #pragma unroll
        for (int ks = 0; ks < 4; ks++) qf[ks] = *(const bf16x8*)(qp + 32*ks);
    }

    int offK[4], offV[4], ldsb[4];
    #pragma unroll
    for (int i = 0; i < 4; i++) {
        int g  = i*256 + wid*64 + lane;
        int jK = g >> 4;
        int dK = ((g & 15) << 3) ^ ((jK & 7) << 3);
        offK[i] = jK * 1024 + dK;
        int jV = ((g >> 3) & 15) * 4 + ((g >> 1) & 3);
        int dV = (g >> 7) * 16 + (g & 1) * 8;
        offV[i] = jV * 1024 + dV;
        ldsb[i] = (i*256 + wid*64) * 8;
    }

    const short* Kg = K + (size_t)b * SEQ * 1024 + kvh * HDIM;
    const short* Vg = V + (size_t)b * SEQ * 1024 + kvh * HDIM;

    f32x4 o[8];
    #pragma unroll
    for (int i = 0; i < 8; i++) o[i] = (f32x4)0.f;
    float m[4]  = {-1e30f, -1e30f, -1e30f, -1e30f};
    float ls[4] = {0.f, 0.f, 0.f, 0.f};

    const int nt = qt + 1;

    auto STAGE = [&](int jb, int bs) {
        const short* Kp = Kg + (size_t)jb * 1024;
        const short* Vp = Vg + (size_t)jb * 1024;
        #pragma unroll
        for (int i = 0; i < 4; i++) {
            gload_lds16(Kp + offK[i], &Ks[bs][0] + ldsb[i]);
            gload_lds16(Vp + offV[i], &Vs[bs][0] + ldsb[i]);
        }
    };

    STAGE(0, 0);
    asm volatile("s_waitcnt vmcnt(0)");
    __syncthreads();

    for (int t = 0; t < nt; t++) {
        const int jbase = t * 64;
        if (t + 1 < nt) STAGE(jbase + 64, (t + 1) & 1);

        if (jbase < qw + 16) {
            const short* Kb = Ks[t & 1];
            lds_short* v3 = (lds_short*)&Vs[t & 1][0];
            unsigned vB = (unsigned)(size_t)v3;

            f32x4 sc[4];
            #pragma unroll
            for (int n = 0; n < 4; n++) sc[n] = (f32x4)0.f;
            #pragma unroll
            for (int ks = 0; ks < 4; ks++) {
                int d0 = ks*32 + l4*8;
                #pragma unroll
                for (int n = 0; n < 4; n++) {
                    int j = n*16 + l15;
                    bf16x8 kb = *(const bf16x8*)(Kb + j*128 + (d0 ^ ((j & 7) << 3)));
                    sc[n] = __builtin_amdgcn_mfma_f32_16x16x32_bf16(qf[ks], kb, sc[n], 0, 0, 0);
                }
            }

            #pragma unroll
            for (int r = 0; r < 4; r++) {
                int q_r = qw + l4*4 + r;
                float mx = -1e30f;
                #pragma unroll
                for (int n = 0; n < 4; n++) {
                    if (jbase + n*16 + l15 > q_r) sc[n][r] = -1e30f;
                    mx = fmaxf(mx, sc[n][r]);
                }
                #pragma unroll
                for (int off = 1; off < 16; off <<= 1)
                    mx = fmaxf(mx, __shfl_xor(mx, off, 64));
                float mn = fmaxf(m[r], mx);
                float cf = __expf(m[r] - mn);
                m[r] = mn;
                float sum = 0.f;
                short* Pr = &Ps[wid][(l4*4 + r) * 72];
                #pragma unroll
                for (int n = 0; n < 4; n++) {
                    float pv = __expf(sc[n][r] - mn);
                    sum += pv;
                    Pr[n*16 + l15] = f2bf(pv);
                }
                ls[r] = ls[r] * cf + sum;
                #pragma unroll
                for (int dt = 0; dt < 8; dt++) o[dt][r] *= cf;
            }

            #pragma unroll
            for (int ks2 = 0; ks2 < 2; ks2++) {
                const short* Pw = &Ps[wid][0];
                bf16x4 a0 = *(const bf16x4*)(Pw + l15*72 + ks2*32 + l4*4);
                bf16x4 a1 = *(const bf16x4*)(Pw + l15*72 + ks2*32 + 16 + l4*4);
                bf16x8 a;
                a[0]=a0[0]; a[1]=a0[1]; a[2]=a0[2]; a[3]=a0[3];
                a[4]=a1[0]; a[5]=a1[1]; a[6]=a1[2]; a[7]=a1[3];

                bf16x4 t1[8], t2[8];
                #pragma unroll
                for (int dt = 0; dt < 8; dt++) {
                    unsigned base = vB + (unsigned)((dt*1024 + ks2*512 + lane*4) * 2);
                    t1[dt] = tr16(base);
                    t2[dt] = tr16(base + 512);
                }
                asm volatile("s_waitcnt lgkmcnt(0)");
                __builtin_amdgcn_sched_barrier(0);
                #pragma unroll
                for (int dt = 0; dt < 8; dt++) {
                    bf16x8 bf;
                    bf[0]=t1[dt][0]; bf[1]=t1[dt][1]; bf[2]=t1[dt][2]; bf[3]=t1[dt][3];
                    bf[4]=t2[dt][0]; bf[5]=t2[dt][1]; bf[6]=t2[dt][2]; bf[7]=t2[dt][3];
                    o[dt] = __builtin_amdgcn_mfma_f32_16x16x32_bf16(a, bf, o[dt], 0, 0, 0);
                }
            }
        }

        asm volatile("s_waitcnt vmcnt(0)");
        __syncthreads();
    }

    #pragma unroll
    for (int off = 1; off < 16; off <<= 1)
        #pragma unroll
        for (int r = 0; r < 4; r++)
            ls[r] += __shfl_xor(ls[r], off, 64);

    _Float16* Op = O + (size_t)(b*SEQ + qw + l4*4) * 4096 + h*HDIM + l15;
    #pragma unroll
    for (int r = 0; r < 4; r++) {
        float inv = 1.f / ls[r];
        #pragma unroll
        for (int dt = 0; dt < 8; dt++)
            Op[(size_t)r * 4096 + dt * 16] = (_Float16)(o[dt][r] * inv);
    }
}

// ---------------------------------------------------------------------------
extern "C" void kernel_launch(void* const* d_in, const int* in_sizes, int n_in,
                              void* d_out, int out_size, void* d_ws, size_t ws_size,
                              hipStream_t stream)
{
    const float* hs  = (const float*)d_in[0];
    const float* q_w = (const float*)d_in[1];
    const float* q_b = (const float*)d_in[2];
    const float* k_w = (const float*)d_in[3];
    const float* k_b = (const float*)d_in[4];
    const float* v_w = (const float*)d_in[5];
    const float* v_b = (const float*)d_in[6];
    const float* o_w = (const float*)d_in[7];
    const float* k_c = (const float*)d_in[8];
    const float* v_c = (const float*)d_in[9];
    float* out = (float*)d_out;

    char* ws = (char*)d_ws;
    _Float16*       hs_hi  = (_Float16*)(ws);
    _Float16*       hs_mid = (_Float16*)(ws + 16777216);
    _Float16*       kvw_hi = (_Float16*)(ws + 33554432);
    _Float16*       kvw_mid= (_Float16*)(ws + 50331648);
    float*          KVp    = (float*)(ws + 67108864);     // [2][2048][2048]
    float*          KVf    = (float*)(ws + 67108864);     // aliases KVp0
    __hip_bfloat16* Krec   = (__hip_bfloat16*)(ws + 83886080);
    __hip_bfloat16* Vrec   = (__hip_bfloat16*)(ws + 88080384);
    float*          cosT   = (float*)(ws + 100663296);
    float*          sinT   = (float*)(ws + 100925440);
    _Float16*       qw_f16 = (_Float16*)(ws + 33554432);
    __hip_bfloat16* Qbf    = (__hip_bfloat16*)(ws + 16777216);
    _Float16*       AttnH  = (_Float16*)(ws + 33554432);
    _Float16*       ow_f16 = (_Float16*)(ws + 50331648);

    rope_table<<<dim3(256), dim3(256), 0, stream>>>(cosT, sinT);

    split_f16<<<dim3(4096), 256, 0, stream>>>(hs, hs_hi, hs_mid, 1048576);
    split_f16<<<dim3(2048), 256, 0, stream>>>(k_w, kvw_hi, kvw_mid, 524288);
    split_f16<<<dim3(2048), 256, 0, stream>>>(v_w, kvw_hi + (size_t)1024*4096,
                                              kvw_mid + (size_t)1024*4096, 524288);

    gemm_kv_3p<<<dim3(16, 16, 2), 256, 0, stream>>>(hs_hi, hs_mid, kvw_hi, kvw_mid, KVp);
    kv_reduce<<<dim3(4096, 2), 256, 0, stream>>>(KVp, k_b, v_b, cosT, sinT);

    cast_f16<<<dim3(8192), 256, 0, stream>>>(q_w, qw_f16, 2097152);
    gemm_q_rope<<<dim3(32, 16), 256, 0, stream>>>(hs_hi, qw_f16, q_b, Qbf, cosT, sinT);

    pq_kernel<<<dim3(256, PQM), 256, 0, stream>>>(KVf,        k_c, Krec, 2048);
    pq_kernel<<<dim3(256, PQM), 256, 0, stream>>>(KVf + 1024, v_c, Vrec, 2048);

    cast_f16<<<dim3(8192), 256, 0, stream>>>(o_w, ow_f16, 2097152);

    attn_mfma<<<dim3(16, 64), 256, 0, stream>>>((const short*)Krec, (const short*)Vrec,
                                                (const short*)Qbf, AttnH);

    gemm_f16_1p<<<dim3(32, 16), 256, 0, stream>>>(AttnH, ow_f16, out, NH*HDIM, 4096);
}

// Round 8
// 458.178 us; speedup vs baseline: 1.2455x; 1.2455x over previous
//
#include <hip/hip_runtime.h>
#include <hip/hip_bf16.h>
#include <math.h>

#define NH   32
#define NKV  8
#define HDIM 128
#define BATCH 2
#define SEQ  1024
#define KSUB 256
#define DSUB 16
#define PQM  8

typedef __attribute__((ext_vector_type(8))) _Float16 f16x8;
typedef __attribute__((ext_vector_type(8))) short bf16x8;
typedef __attribute__((ext_vector_type(4))) short bf16x4;
typedef __attribute__((ext_vector_type(4))) float f32x4;
typedef __attribute__((address_space(3))) short lds_short;

__device__ inline short f2bf(float x) {
    unsigned u = __builtin_bit_cast(unsigned, x);
    unsigned r = (u + 0x7fff + ((u >> 16) & 1)) >> 16;
    return (short)r;
}

__device__ inline void gload_lds16(const void* g, void* l) {
    __builtin_amdgcn_global_load_lds(
        (const __attribute__((address_space(1))) unsigned*)g,
        (__attribute__((address_space(3))) unsigned*)l, 16, 0, 0);
}

__device__ inline bf16x4 tr16(unsigned byte_addr) {
    bf16x4 r;
    asm volatile("ds_read_b64_tr_b16 %0, %1" : "=v"(r) : "v"(byte_addr));
    return r;
}

// ---------------------------------------------------------------------------
// Merged fp32 -> fp16 2-term splits: hs (4096 blocks), k_w (2048), v_w (2048).
// x = hi + mid * 2^-12.
// ---------------------------------------------------------------------------
__global__ void split_all(const float* __restrict__ hs,
                          const float* __restrict__ k_w, const float* __restrict__ v_w,
                          _Float16* __restrict__ hs_hi, _Float16* __restrict__ hs_mid,
                          _Float16* __restrict__ kvw_hi, _Float16* __restrict__ kvw_mid)
{
    int blk = blockIdx.x;
    const float* x; _Float16 *hi, *mid; int i;
    if (blk < 4096)      { x = hs;  hi = hs_hi;  mid = hs_mid;  i = blk*256 + threadIdx.x; }
    else if (blk < 6144) { x = k_w; hi = kvw_hi; mid = kvw_mid; i = (blk-4096)*256 + threadIdx.x; }
    else                 { x = v_w; hi = kvw_hi + 4194304; mid = kvw_mid + 4194304;
                           i = (blk-6144)*256 + threadIdx.x; }
    float4 v0 = ((const float4*)x)[2*i];
    float4 v1 = ((const float4*)x)[2*i + 1];
    float v[8] = {v0.x, v0.y, v0.z, v0.w, v1.x, v1.y, v1.z, v1.w};
    f16x8 h, m;
    #pragma unroll
    for (int j = 0; j < 8; j++) {
        _Float16 hh = (_Float16)v[j];
        h[j] = hh;
        m[j] = (_Float16)((v[j] - (float)hh) * 4096.f);
    }
    ((f16x8*)hi)[i]  = h;
    ((f16x8*)mid)[i] = m;
}

__global__ void cast_f16(const float* __restrict__ x, _Float16* __restrict__ y, int n8)
{
    int i = blockIdx.x * 256 + threadIdx.x;
    if (i < n8) {
        float4 v0 = ((const float4*)x)[2*i];
        float4 v1 = ((const float4*)x)[2*i + 1];
        float v[8] = {v0.x, v0.y, v0.z, v0.w, v1.x, v1.y, v1.z, v1.w};
        f16x8 h;
        #pragma unroll
        for (int j = 0; j < 8; j++) h[j] = (_Float16)v[j];
        ((f16x8*)y)[i] = h;
    }
}

// ---------------------------------------------------------------------------
// KV projection, 3-pass precision-split, split-K=2, dbuf, BK=32 (at its
// structure ceiling ~908 TF effective; unchanged from round 7).
// ---------------------------------------------------------------------------
__global__ __launch_bounds__(256, 2) void gemm_kv_3p(
    const _Float16* __restrict__ Ahi, const _Float16* __restrict__ Ami,
    const _Float16* __restrict__ Whi, const _Float16* __restrict__ Wmi,
    float* __restrict__ Cp)
{
    __shared__ _Float16 sAh[2][128 * 32];
    __shared__ _Float16 sAm[2][128 * 32];
    __shared__ _Float16 sWh[2][128 * 32];
    __shared__ _Float16 sWm[2][128 * 32];

    const int tid = threadIdx.x;
    const int wid = tid >> 6, lane = tid & 63;
    const int l15 = lane & 15, l4 = lane >> 4;
    const int col0 = blockIdx.x * 128, row0 = blockIdx.y * 128;
    const int kz = blockIdx.z;
    const int wr = (wid >> 1) * 64, wc = (wid & 1) * 64;
    const int cx8 = (l4 ^ ((l15 >> 1) & 3)) * 8;

    f32x4 am[4][4], ax[4][4];
    #pragma unroll
    for (int m = 0; m < 4; m++)
        #pragma unroll
        for (int n = 0; n < 4; n++) { am[m][n] = (f32x4)0.f; ax[m][n] = (f32x4)0.f; }

    const int ci0 = tid, ci1 = tid + 256;
    const int r0 = ci0 >> 2, c0 = ((ci0 & 3) ^ ((ci0 >> 3) & 3)) * 8;
    const int r1 = ci1 >> 2, c1 = ((ci1 & 3) ^ ((ci1 >> 3) & 3)) * 8;
    const size_t kb = (size_t)kz * 2048;
    const _Float16* pAh0 = Ahi + (size_t)(row0 + r0) * 4096 + kb + c0;
    const _Float16* pAh1 = Ahi + (size_t)(row0 + r1) * 4096 + kb + c1;
    const _Float16* pAm0 = Ami + (size_t)(row0 + r0) * 4096 + kb + c0;
    const _Float16* pAm1 = Ami + (size_t)(row0 + r1) * 4096 + kb + c1;
    const _Float16* pWh0 = Whi + (size_t)(col0 + r0) * 4096 + kb + c0;
    const _Float16* pWh1 = Whi + (size_t)(col0 + r1) * 4096 + kb + c1;
    const _Float16* pWm0 = Wmi + (size_t)(col0 + r0) * 4096 + kb + c0;
    const _Float16* pWm1 = Wmi + (size_t)(col0 + r1) * 4096 + kb + c1;

    auto STAGE = [&](int bs, int k0) {
        gload_lds16(pAh0 + k0, &sAh[bs][0] + ci0 * 8);
        gload_lds16(pAh1 + k0, &sAh[bs][0] + ci1 * 8);
        gload_lds16(pAm0 + k0, &sAm[bs][0] + ci0 * 8);
        gload_lds16(pAm1 + k0, &sAm[bs][0] + ci1 * 8);
        gload_lds16(pWh0 + k0, &sWh[bs][0] + ci0 * 8);
        gload_lds16(pWh1 + k0, &sWh[bs][0] + ci1 * 8);
        gload_lds16(pWm0 + k0, &sWm[bs][0] + ci0 * 8);
        gload_lds16(pWm1 + k0, &sWm[bs][0] + ci1 * 8);
    };

    STAGE(0, 0);
    __syncthreads();
    int cur = 0;

    for (int k0 = 0; k0 < 2048; k0 += 32) {
        if (k0 + 32 < 2048) STAGE(cur ^ 1, k0 + 32);

        f16x8 ah[4], amv[4], bh[4], bm[4];
        #pragma unroll
        for (int m = 0; m < 4; m++) {
            ah[m]  = *(const f16x8*)(&sAh[cur][0] + (wr + m*16 + l15) * 32 + cx8);
            amv[m] = *(const f16x8*)(&sAm[cur][0] + (wr + m*16 + l15) * 32 + cx8);
        }
        #pragma unroll
        for (int n = 0; n < 4; n++) {
            bh[n] = *(const f16x8*)(&sWh[cur][0] + (wc + n*16 + l15) * 32 + cx8);
            bm[n] = *(const f16x8*)(&sWm[cur][0] + (wc + n*16 + l15) * 32 + cx8);
        }
        #pragma unroll
        for (int m = 0; m < 4; m++)
            #pragma unroll
            for (int n = 0; n < 4; n++) {
                am[m][n] = __builtin_amdgcn_mfma_f32_16x16x32_f16(ah[m],  bh[n], am[m][n], 0, 0, 0);
                ax[m][n] = __builtin_amdgcn_mfma_f32_16x16x32_f16(ah[m],  bm[n], ax[m][n], 0, 0, 0);
                ax[m][n] = __builtin_amdgcn_mfma_f32_16x16x32_f16(amv[m], bh[n], ax[m][n], 0, 0, 0);
            }
        __syncthreads();
        cur ^= 1;
    }

    float* base = Cp + (size_t)kz * 2048 * 2048;
    const float s = 1.f / 4096.f;
    #pragma unroll
    for (int m = 0; m < 4; m++) {
        #pragma unroll
        for (int r = 0; r < 4; r++) {
            float* p = base + (size_t)(row0 + wr + m*16 + l4*4 + r) * 2048 + col0 + wc + l15;
            #pragma unroll
            for (int n = 0; n < 4; n++)
                p[n * 16] = am[m][n][r] + ax[m][n][r] * s;
        }
    }
}

// ---------------------------------------------------------------------------
// Split-K reduce + bias, fused K-RoPE. (unchanged)
// ---------------------------------------------------------------------------
__global__ void kv_reduce(float* __restrict__ KVp,
                          const float* __restrict__ bK, const float* __restrict__ bV,
                          const float* __restrict__ cosT, const float* __restrict__ sinT)
{
    int t = blockIdx.x * 256 + threadIdx.x;
    float* P0 = KVp;
    const float* P1 = KVp + (size_t)2048 * 2048;
    if (blockIdx.y == 0) {
        int i  = t & 63;
        int h  = (t >> 6) & 7;
        int rr = t >> 9;
        int s  = rr & (SEQ - 1);
        size_t o = (size_t)rr * 2048 + h * 128 + i;
        float x1 = P0[o]      + P1[o]      + bK[h*128 + i];
        float x2 = P0[o + 64] + P1[o + 64] + bK[h*128 + i + 64];
        float c  = cosT[s*64 + i];
        float sv = sinT[s*64 + i];
        P0[o]      = x1 * c - x2 * sv;
        P0[o + 64] = x2 * c + x1 * sv;
    } else {
        int j  = t & 511;
        int rr = t >> 9;
        size_t o = (size_t)rr * 2048 + 1024 + j;
        P0[o]       = P0[o]       + P1[o]       + bV[j];
        P0[o + 512] = P0[o + 512] + P1[o + 512] + bV[j + 512];
    }
}

// ---------------------------------------------------------------------------
// Q projection, fused RoPE+scale+bf16, BK=64, dbuf, row-XOR granule swizzle.
// LDS slot g of row r holds source k-granule (g ^ (r&7)).
// ---------------------------------------------------------------------------
__global__ __launch_bounds__(256) void gemm_q_rope(
    const _Float16* __restrict__ A, const _Float16* __restrict__ W,
    const float* __restrict__ bias, __hip_bfloat16* __restrict__ Qbf,
    const float* __restrict__ cosT, const float* __restrict__ sinT)
{
    __shared__ _Float16 Al[2][128 * 64];
    __shared__ _Float16 Bl[2][128 * 64];

    const int tid = threadIdx.x;
    const int wid = tid >> 6, lane = tid & 63;
    const int l15 = lane & 15, l4 = lane >> 4;
    const int row0 = blockIdx.y * 128, col0 = blockIdx.x * 128;
    const int wr = (wid >> 1) * 64, wc = (wid & 1) * 32;
    const int K = 4096;
    const int sx = l15 & 7;

    f32x4 acc[4][4];
    #pragma unroll
    for (int m = 0; m < 4; m++)
        #pragma unroll
        for (int n = 0; n < 4; n++) acc[m][n] = (f32x4)0.f;

    const _Float16* Agp[4]; const _Float16* Wgp[4]; int ldst[4];
    #pragma unroll
    for (int j = 0; j < 4; j++) {
        int ci = tid + j*256;
        int r  = ci >> 3;
        int c  = ((ci & 7) ^ (r & 7)) * 8;
        Agp[j] = A + (size_t)(row0 + r) * K + c;
        Wgp[j] = W + (size_t)(col0 + r) * K + c;
        ldst[j] = ci * 8;
    }

    auto STAGE = [&](int bs, int k0) {
        #pragma unroll
        for (int j = 0; j < 4; j++) {
            gload_lds16(Agp[j] + k0, &Al[bs][0] + ldst[j]);
            gload_lds16(Wgp[j] + k0, &Bl[bs][0] + ldst[j]);
        }
    };

    STAGE(0, 0);
    __syncthreads();
    int cur = 0;

    for (int k0 = 0; k0 < K; k0 += 64) {
        if (k0 + 64 < K) STAGE(cur ^ 1, k0 + 64);

        #pragma unroll
        for (int kh = 0; kh < 2; kh++) {
            const int g = ((kh*4 + l4) ^ sx) * 8;
            f16x8 af[4], bfr[4];
            #pragma unroll
            for (int m = 0; m < 4; m++)
                af[m] = *(const f16x8*)(&Al[cur][0] + (wr + m*16 + l15) * 64 + g);
            #pragma unroll
            for (int n = 0; n < 4; n++) {
                int fc = wc + (n & 1) * 16 + (n >> 1) * 64;
                bfr[n] = *(const f16x8*)(&Bl[cur][0] + (fc + l15) * 64 + g);
            }
            #pragma unroll
            for (int m = 0; m < 4; m++)
                #pragma unroll
                for (int n = 0; n < 4; n++)
                    acc[m][n] = __builtin_amdgcn_mfma_f32_16x16x32_f16(af[m], bfr[n], acc[m][n], 0, 0, 0);
        }
        __syncthreads();
        cur ^= 1;
    }

    const float scale = 0.08838834764831845f;
    #pragma unroll
    for (int m = 0; m < 4; m++) {
        #pragma unroll
        for (int r = 0; r < 4; r++) {
            int rr = row0 + wr + m*16 + l4*4 + r;
            int s  = rr & (SEQ - 1);
            #pragma unroll
            for (int n = 0; n < 2; n++) {
                int i = wc + n*16 + l15;
                float x1 = acc[m][n][r]     + bias[col0 + i];
                float x2 = acc[m][n + 2][r] + bias[col0 + i + 64];
                float c  = cosT[s*64 + i];
                float sv = sinT[s*64 + i];
                Qbf[(size_t)rr * 4096 + col0 + i]      = __float2bfloat16((x1*c - x2*sv) * scale);
                Qbf[(size_t)rr * 4096 + col0 + i + 64] = __float2bfloat16((x2*c + x1*sv) * scale);
            }
        }
    }
}

// ---------------------------------------------------------------------------
// O projection, BK=64, dbuf, row-XOR granule swizzle.
// ---------------------------------------------------------------------------
__global__ __launch_bounds__(256) void gemm_f16_1p(
    const _Float16* __restrict__ A, const _Float16* __restrict__ W,
    float* __restrict__ C, int N, int K)
{
    __shared__ _Float16 Al[2][128 * 64];
    __shared__ _Float16 Bl[2][128 * 64];

    const int tid = threadIdx.x;
    const int wid = tid >> 6, lane = tid & 63;
    const int l15 = lane & 15, l4 = lane >> 4;
    const int row0 = blockIdx.y * 128, col0 = blockIdx.x * 128;
    const int wr = (wid >> 1) * 64, wc = (wid & 1) * 64;
    const int sx = l15 & 7;

    f32x4 acc[4][4];
    #pragma unroll
    for (int m = 0; m < 4; m++)
        #pragma unroll
        for (int n = 0; n < 4; n++) acc[m][n] = (f32x4)0.f;

    const _Float16* Agp[4]; const _Float16* Wgp[4]; int ldst[4];
    #pragma unroll
    for (int j = 0; j < 4; j++) {
        int ci = tid + j*256;
        int r  = ci >> 3;
        int c  = ((ci & 7) ^ (r & 7)) * 8;
        Agp[j] = A + (size_t)(row0 + r) * K + c;
        Wgp[j] = W + (size_t)(col0 + r) * K + c;
        ldst[j] = ci * 8;
    }

    auto STAGE = [&](int bs, int k0) {
        #pragma unroll
        for (int j = 0; j < 4; j++) {
            gload_lds16(Agp[j] + k0, &Al[bs][0] + ldst[j]);
            gload_lds16(Wgp[j] + k0, &Bl[bs][0] + ldst[j]);
        }
    };

    STAGE(0, 0);
    __syncthreads();
    int cur = 0;

    for (int k0 = 0; k0 < K; k0 += 64) {
        if (k0 + 64 < K) STAGE(cur ^ 1, k0 + 64);

        #pragma unroll
        for (int kh = 0; kh < 2; kh++) {
            const int g = ((kh*4 + l4) ^ sx) * 8;
            f16x8 af[4], bfr[4];
            #pragma unroll
            for (int m = 0; m < 4; m++)
                af[m] = *(const f16x8*)(&Al[cur][0] + (wr + m*16 + l15) * 64 + g);
            #pragma unroll
            for (int n = 0; n < 4; n++)
                bfr[n] = *(const f16x8*)(&Bl[cur][0] + (wc + n*16 + l15) * 64 + g);
            #pragma unroll
            for (int m = 0; m < 4; m++)
                #pragma unroll
                for (int n = 0; n < 4; n++)
                    acc[m][n] = __builtin_amdgcn_mfma_f32_16x16x32_f16(af[m], bfr[n], acc[m][n], 0, 0, 0);
        }
        __syncthreads();
        cur ^= 1;
    }

    #pragma unroll
    for (int m = 0; m < 4; m++) {
        #pragma unroll
        for (int r = 0; r < 4; r++) {
            float* Cp = C + (size_t)(row0 + wr + m*16 + l4*4 + r) * N + col0 + wc + l15;
            #pragma unroll
            for (int n = 0; n < 4; n++)
                Cp[n * 16] = acc[m][n][r];
        }
    }
}

// ---------------------------------------------------------------------------
__global__ void rope_table(float* __restrict__ cosT, float* __restrict__ sinT)
{
    int idx = blockIdx.x * 256 + threadIdx.x;
    int s = idx >> 6, i = idx & 63;
    float inv_f = (float)pow(1.0e6, -(double)i / 64.0);
    float freq  = (float)s * inv_f;
    cosT[idx] = (float)cos((double)freq);
    sinT[idx] = (float)sin((double)freq);
}

// ---------------------------------------------------------------------------
// Centroid squared norms: CCt[z*2048 + m*256 + k].
// ---------------------------------------------------------------------------
__global__ void pq_cc(const float* __restrict__ k_c, const float* __restrict__ v_c,
                      float* __restrict__ CCt)
{
    int i = blockIdx.x * 256 + threadIdx.x;       // 4096
    const float* c = (i < 2048 ? k_c : v_c) + (size_t)(i & 2047) * 16;
    float s = 0.f;
    #pragma unroll
    for (int d = 0; d < 16; d++) s = fmaf(c[d], c[d], s);
    CCt[i] = s;
}

// ---------------------------------------------------------------------------
// PQ round-trip v3: no LDS. Uniform k -> centroid reads go through the scalar
// pipe (s_load); score = fma(-2, dot, CC[k]) (xx dropped: fp32 add is
// monotonic, argmin preserved). Strict < keeps first min = jnp.argmin.
// grid (64, PQM, 2): z=0 -> K, z=1 -> V.
// ---------------------------------------------------------------------------
__global__ __launch_bounds__(256) void pq_kernel(
    const float* __restrict__ X, const float* __restrict__ k_c,
    const float* __restrict__ v_c, const float* __restrict__ CCt,
    __hip_bfloat16* __restrict__ Krec, __hip_bfloat16* __restrict__ Vrec)
{
    const int z = blockIdx.z, m = blockIdx.y;
    const float* cent = (z ? v_c : k_c) + (size_t)m * KSUB * DSUB;
    const float* cc   = CCt + z * (PQM * KSUB) + m * KSUB;

    const int p  = blockIdx.x * 256 + threadIdx.x;
    const int s_ = p & (SEQ - 1);
    const int bh = p >> 10;
    const int b  = bh >> 3, h = bh & 7;
    const float* x = X + (size_t)(b*SEQ + s_) * 2048 + z*1024 + h*HDIM + m*DSUB;

    float xv[DSUB];
    #pragma unroll
    for (int d = 0; d < DSUB; d++) xv[d] = x[d];

    float best = INFINITY; int bk = 0;
    #pragma unroll 4
    for (int k = 0; k < KSUB; k++) {
        const float* ck = cent + k*DSUB;
        float dot = 0.f;
        #pragma unroll
        for (int d = 0; d < DSUB; d++) dot = fmaf(xv[d], ck[d], dot);
        float sc = fmaf(-2.f, dot, cc[k]);
        if (sc < best) { best = sc; bk = k; }
    }

    short* r = (short*)((z ? Vrec : Krec) + (size_t)(b*SEQ + s_) * 1024 + h*HDIM + m*DSUB);
    const float* cb = cent + bk*DSUB;
    bf16x8 o0, o1;
    #pragma unroll
    for (int j = 0; j < 8; j++) { o0[j] = f2bf(cb[j]); o1[j] = f2bf(cb[8+j]); }
    *(bf16x8*)r       = o0;
    *(bf16x8*)(r + 8) = o1;
}

// ---------------------------------------------------------------------------
// MFMA flash attention (unchanged).
// ---------------------------------------------------------------------------
__global__ __launch_bounds__(256) void attn_mfma(
    const short* __restrict__ K, const short* __restrict__ V,
    const short* __restrict__ Qbf, _Float16* __restrict__ O)
{
    __shared__ short Ks[2][64 * 128];
    __shared__ short Vs[2][64 * 128];
    __shared__ short Ps[4][16 * 72];

    const int tid = threadIdx.x;
    const int wid = tid >> 6, lane = tid & 63;
    const int l15 = lane & 15, l4 = lane >> 4;
    const int qt  = gridDim.x - 1 - blockIdx.x;
    const int qb  = qt * 64;
    const int h   = blockIdx.y & 31, b = blockIdx.y >> 5;
    const int kvh = h >> 2;
    const int qw  = qb + wid * 16;

    bf16x8 qf[4];
    {
        const short* qp = Qbf + (size_t)(b*SEQ + qw + l15) * 4096 + h*HDIM + l4*8;
        #pragma unroll
        for (int ks = 0; ks < 4; ks++) qf[ks] = *(const bf16x8*)(qp + 32*ks);
    }

    int offK[4], offV[4], ldsb[4];
    #pragma unroll
    for (int i = 0; i < 4; i++) {
        int g  = i*256 + wid*64 + lane;
        int jK = g >> 4;
        int dK = ((g & 15) << 3) ^ ((jK & 7) << 3);
        offK[i] = jK * 1024 + dK;
        int jV = ((g >> 3) & 15) * 4 + ((g >> 1) & 3);
        int dV = (g >> 7) * 16 + (g & 1) * 8;
        offV[i] = jV * 1024 + dV;
        ldsb[i] = (i*256 + wid*64) * 8;
    }

    const short* Kg = K + (size_t)b * SEQ * 1024 + kvh * HDIM;
    const short* Vg = V + (size_t)b * SEQ * 1024 + kvh * HDIM;

    f32x4 o[8];
    #pragma unroll
    for (int i = 0; i < 8; i++) o[i] = (f32x4)0.f;
    float m[4]  = {-1e30f, -1e30f, -1e30f, -1e30f};
    float ls[4] = {0.f, 0.f, 0.f, 0.f};

    const int nt = qt + 1;

    auto STAGE = [&](int jb, int bs) {
        const short* Kp = Kg + (size_t)jb * 1024;
        const short* Vp = Vg + (size_t)jb * 1024;
        #pragma unroll
        for (int i = 0; i < 4; i++) {
            gload_lds16(Kp + offK[i], &Ks[bs][0] + ldsb[i]);
            gload_lds16(Vp + offV[i], &Vs[bs][0] + ldsb[i]);
        }
    };

    STAGE(0, 0);
    asm volatile("s_waitcnt vmcnt(0)");
    __syncthreads();

    for (int t = 0; t < nt; t++) {
        const int jbase = t * 64;
        if (t + 1 < nt) STAGE(jbase + 64, (t + 1) & 1);

        if (jbase < qw + 16) {
            const short* Kb = Ks[t & 1];
            lds_short* v3 = (lds_short*)&Vs[t & 1][0];
            unsigned vB = (unsigned)(size_t)v3;

            f32x4 sc[4];
            #pragma unroll
            for (int n = 0; n < 4; n++) sc[n] = (f32x4)0.f;
            #pragma unroll
            for (int ks = 0; ks < 4; ks++) {
                int d0 = ks*32 + l4*8;
                #pragma unroll
                for (int n = 0; n < 4; n++) {
                    int j = n*16 + l15;
                    bf16x8 kb = *(const bf16x8*)(Kb + j*128 + (d0 ^ ((j & 7) << 3)));
                    sc[n] = __builtin_amdgcn_mfma_f32_16x16x32_bf16(qf[ks], kb, sc[n], 0, 0, 0);
                }
            }

            #pragma unroll
            for (int r = 0; r < 4; r++) {
                int q_r = qw + l4*4 + r;
                float mx = -1e30f;
                #pragma unroll
                for (int n = 0; n < 4; n++) {
                    if (jbase + n*16 + l15 > q_r) sc[n][r] = -1e30f;
                    mx = fmaxf(mx, sc[n][r]);
                }
                #pragma unroll
                for (int off = 1; off < 16; off <<= 1)
                    mx = fmaxf(mx, __shfl_xor(mx, off, 64));
                float mn = fmaxf(m[r], mx);
                float cf = __expf(m[r] - mn);
                m[r] = mn;
                float sum = 0.f;
                short* Pr = &Ps[wid][(l4*4 + r) * 72];
                #pragma unroll
                for (int n = 0; n < 4; n++) {
                    float pv = __expf(sc[n][r] - mn);
                    sum += pv;
                    Pr[n*16 + l15] = f2bf(pv);
                }
                ls[r] = ls[r] * cf + sum;
                #pragma unroll
                for (int dt = 0; dt < 8; dt++) o[dt][r] *= cf;
            }

            #pragma unroll
            for (int ks2 = 0; ks2 < 2; ks2++) {
                const short* Pw = &Ps[wid][0];
                bf16x4 a0 = *(const bf16x4*)(Pw + l15*72 + ks2*32 + l4*4);
                bf16x4 a1 = *(const bf16x4*)(Pw + l15*72 + ks2*32 + 16 + l4*4);
                bf16x8 a;
                a[0]=a0[0]; a[1]=a0[1]; a[2]=a0[2]; a[3]=a0[3];
                a[4]=a1[0]; a[5]=a1[1]; a[6]=a1[2]; a[7]=a1[3];

                bf16x4 t1[8], t2[8];
                #pragma unroll
                for (int dt = 0; dt < 8; dt++) {
                    unsigned base = vB + (unsigned)((dt*1024 + ks2*512 + lane*4) * 2);
                    t1[dt] = tr16(base);
                    t2[dt] = tr16(base + 512);
                }
                asm volatile("s_waitcnt lgkmcnt(0)");
                __builtin_amdgcn_sched_barrier(0);
                #pragma unroll
                for (int dt = 0; dt < 8; dt++) {
                    bf16x8 bf;
                    bf[0]=t1[dt][0]; bf[1]=t1[dt][1]; bf[2]=t1[dt][2]; bf[3]=t1[dt][3];
                    bf[4]=t2[dt][0]; bf[5]=t2[dt][1]; bf[6]=t2[dt][2]; bf[7]=t2[dt][3];
                    o[dt] = __builtin_amdgcn_mfma_f32_16x16x32_bf16(a, bf, o[dt], 0, 0, 0);
                }
            }
        }

        asm volatile("s_waitcnt vmcnt(0)");
        __syncthreads();
    }

    #pragma unroll
    for (int off = 1; off < 16; off <<= 1)
        #pragma unroll
        for (int r = 0; r < 4; r++)
            ls[r] += __shfl_xor(ls[r], off, 64);

    _Float16* Op = O + (size_t)(b*SEQ + qw + l4*4) * 4096 + h*HDIM + l15;
    #pragma unroll
    for (int r = 0; r < 4; r++) {
        float inv = 1.f / ls[r];
        #pragma unroll
        for (int dt = 0; dt < 8; dt++)
            Op[(size_t)r * 4096 + dt * 16] = (_Float16)(o[dt][r] * inv);
    }
}

// ---------------------------------------------------------------------------
extern "C" void kernel_launch(void* const* d_in, const int* in_sizes, int n_in,
                              void* d_out, int out_size, void* d_ws, size_t ws_size,
                              hipStream_t stream)
{
    const float* hs  = (const float*)d_in[0];
    const float* q_w = (const float*)d_in[1];
    const float* q_b = (const float*)d_in[2];
    const float* k_w = (const float*)d_in[3];
    const float* k_b = (const float*)d_in[4];
    const float* v_w = (const float*)d_in[5];
    const float* v_b = (const float*)d_in[6];
    const float* o_w = (const float*)d_in[7];
    const float* k_c = (const float*)d_in[8];
    const float* v_c = (const float*)d_in[9];
    float* out = (float*)d_out;

    char* ws = (char*)d_ws;
    _Float16*       hs_hi  = (_Float16*)(ws);
    _Float16*       hs_mid = (_Float16*)(ws + 16777216);
    _Float16*       kvw_hi = (_Float16*)(ws + 33554432);
    _Float16*       kvw_mid= (_Float16*)(ws + 50331648);
    float*          KVp    = (float*)(ws + 67108864);     // [2][2048][2048]
    float*          KVf    = (float*)(ws + 67108864);     // aliases KVp0
    __hip_bfloat16* Krec   = (__hip_bfloat16*)(ws + 83886080);
    __hip_bfloat16* Vrec   = (__hip_bfloat16*)(ws + 88080384);
    float*          cosT   = (float*)(ws + 100663296);
    float*          sinT   = (float*)(ws + 100925440);
    float*          CCt    = (float*)(ws + 101187584);    // 16 KB
    _Float16*       qw_f16 = (_Float16*)(ws + 33554432);
    __hip_bfloat16* Qbf    = (__hip_bfloat16*)(ws + 16777216);
    _Float16*       AttnH  = (_Float16*)(ws + 33554432);
    _Float16*       ow_f16 = (_Float16*)(ws + 50331648);

    rope_table<<<dim3(256), dim3(256), 0, stream>>>(cosT, sinT);
    pq_cc<<<dim3(16), 256, 0, stream>>>(k_c, v_c, CCt);

    split_all<<<dim3(8192), 256, 0, stream>>>(hs, k_w, v_w, hs_hi, hs_mid, kvw_hi, kvw_mid);

    gemm_kv_3p<<<dim3(16, 16, 2), 256, 0, stream>>>(hs_hi, hs_mid, kvw_hi, kvw_mid, KVp);
    kv_reduce<<<dim3(4096, 2), 256, 0, stream>>>(KVp, k_b, v_b, cosT, sinT);

    cast_f16<<<dim3(8192), 256, 0, stream>>>(q_w, qw_f16, 2097152);
    gemm_q_rope<<<dim3(32, 16), 256, 0, stream>>>(hs_hi, qw_f16, q_b, Qbf, cosT, sinT);

    pq_kernel<<<dim3(64, PQM, 2), 256, 0, stream>>>(KVf, k_c, v_c, CCt, Krec, Vrec);

    cast_f16<<<dim3(8192), 256, 0, stream>>>(o_w, ow_f16, 2097152);

    attn_mfma<<<dim3(16, 64), 256, 0, stream>>>((const short*)Krec, (const short*)Vrec,
                                                (const short*)Qbf, AttnH);

    gemm_f16_1p<<<dim3(32, 16), 256, 0, stream>>>(AttnH, ow_f16, out, NH*HDIM, 4096);
}